// Round 4
// baseline (335.627 us; speedup 1.0000x reference)
//
#include <hip/hip_runtime.h>
#include <math.h>

#define D4    512           // 2048 dims / 4 per float4
#define NTOK  16384         // B*T
#define NW6   (NTOK * 6)    // weights (and indices) chunk size

#define DOT4(a, b) ((a).x*(b).x + (a).y*(b).y + (a).z*(b).z + (a).w*(b).w)

// One wave = 4 groups of 16 lanes; each group owns 2 tokens (8 tok/wave).
// Explicit distance-1 register prefetch: iteration c computes on regs loaded
// during iteration c-1, while issuing all 20 float4 loads for c+1 up front.
// One vmcnt wait per iteration instead of ~19 serialized round-trips.
// __launch_bounds__(256,2): VGPR cap 256 so the double-buffer fits.
__global__ __launch_bounds__(256, 2) void router_kernel(
    const float* __restrict__ x,
    const float* __restrict__ We,
    const float* __restrict__ Wg,
    float* __restrict__ out,
    unsigned int* __restrict__ gcounts)
{
    __shared__ unsigned int lcnt[16];
    const int tid = threadIdx.x;
    if (tid < 16) lcnt[tid] = 0u;
    __syncthreads();

    const int wave = tid >> 6;
    const int lane = tid & 63;
    const int grp  = lane >> 4;   // 0..3 : token pair within wave
    const int l16  = lane & 15;

    const int tok0 = (blockIdx.x * 4 + wave) * 8;
    const int ta = tok0 + grp * 2;
    const int tb = ta + 1;

    const float4* __restrict__ x4  = reinterpret_cast<const float4*>(x);
    const float4* __restrict__ We4 = reinterpret_cast<const float4*>(We);
    const float4* __restrict__ Wg4 = reinterpret_cast<const float4*>(Wg);
    const float4* __restrict__ xa_p = x4 + (size_t)ta * D4;
    const float4* __restrict__ xb_p = x4 + (size_t)tb * D4;

    // Wave-uniform row bases (SGPRs). Index is always an unrolled constant.
    const float4* __restrict__ wrow[18];
#pragma unroll
    for (int e = 0; e < 16; ++e) wrow[e] = We4 + (size_t)e * D4;
    wrow[16] = Wg4;
    wrow[17] = Wg4 + D4;

    float acca[18], accb[18];
#pragma unroll
    for (int e = 0; e < 18; ++e) { acca[e] = 0.f; accb[e] = 0.f; }

    // ---- software pipeline: preload chunk 0 ----
    float4 cxa, cxb, cw[18];
    float4 nxa, nxb, nw[18];
    {
        const int off = l16;
        cxa = xa_p[off];
        cxb = xb_p[off];
#pragma unroll
        for (int e = 0; e < 18; ++e) cw[e] = wrow[e][off];
    }

#pragma unroll 2
    for (int c = 0; c < 32; ++c) {
        // Issue next chunk's loads first (independent of current compute).
        if (c + 1 < 32) {
            const int noff = (c + 1) * 16 + l16;
            nxa = xa_p[noff];
            nxb = xb_p[noff];
#pragma unroll
            for (int e = 0; e < 18; ++e) nw[e] = wrow[e][noff];
        }
        // Compute on current regs (loaded one iteration ago).
#pragma unroll
        for (int e = 0; e < 18; ++e) {
            acca[e] += DOT4(cw[e], cxa);
            accb[e] += DOT4(cw[e], cxb);
        }
        // Rotate (renamed away by unroll).
        cxa = nxa; cxb = nxb;
#pragma unroll
        for (int e = 0; e < 18; ++e) cw[e] = nw[e];
    }

    // Butterfly-reduce across the 16 lanes of the group (masks stay in-group).
#pragma unroll
    for (int e = 0; e < 18; ++e) {
        float va = acca[e], vb = accb[e];
#pragma unroll
        for (int m = 8; m >= 1; m >>= 1) {
            va += __shfl_xor(va, m, 64);
            vb += __shfl_xor(vb, m, 64);
        }
        acca[e] = va; accb[e] = vb;
    }

    // Lane 0 routes token ta; lane 1 routes token tb. Static selects only.
    if (l16 < 2) {
        const int tok = ta + l16;
        float s[16];
#pragma unroll
        for (int e = 0; e < 16; ++e) s[e] = (l16 == 0) ? acca[e] : accb[e];
        const float gs0 = (l16 == 0) ? acca[16] : accb[16];
        const float gs1 = (l16 == 0) ? acca[17] : accb[17];
        const float g0 = 1.f / (1.f + expf(-gs0));
        const float g1 = 1.f / (1.f + expf(-gs1));

        // --- Group A: experts 0..7, top-1 of softmax ---
        int aidx = 0; float amax = s[0];
#pragma unroll
        for (int i = 1; i < 8; ++i)
            if (s[i] > amax) { amax = s[i]; aidx = i; }
        float asum = 0.f;
#pragma unroll
        for (int i = 0; i < 8; ++i) asum += expf(s[i] - amax);
        const float a_best = 1.f / asum;

        // --- Group B: experts 8..11, top-1, gated by g0 ---
        int bidx = 0; float bmax = s[8];
#pragma unroll
        for (int i = 1; i < 4; ++i)
            if (s[8 + i] > bmax) { bmax = s[8 + i]; bidx = i; }
        float bsum = 0.f;
#pragma unroll
        for (int i = 0; i < 4; ++i) bsum += expf(s[8 + i] - bmax);
        const float b_w = (g0 > 0.15f) ? ((1.f / bsum) * g0) : 0.f;

        // --- Group C: experts 12..15, top-2 of softmax, gated by g1 ---
        int c1 = 0; float cmax = s[12];
#pragma unroll
        for (int i = 1; i < 4; ++i)
            if (s[12 + i] > cmax) { cmax = s[12 + i]; c1 = i; }
        float csum = 0.f;
#pragma unroll
        for (int i = 0; i < 4; ++i) csum += expf(s[12 + i] - cmax);
        int c2 = -1; float c2v = -1e30f;
#pragma unroll
        for (int i = 0; i < 4; ++i)
            if (i != c1 && s[12 + i] > c2v) { c2v = s[12 + i]; c2 = i; }
        const float cg   = (g1 > 0.15f) ? g1 : 0.f;
        const float c_w1 = (1.f / csum) * cg;
        const float c_w2 = (expf(c2v - cmax) / csum) * cg;

        // --- normalize and write ---
        const float inv = 1.f / (a_best + b_w + c_w1 + c_w2 + 1e-8f);
        float2* ow = reinterpret_cast<float2*>(out + (size_t)tok * 6);
        ow[0] = make_float2(a_best * inv, b_w * inv);
        ow[1] = make_float2(c_w1 * inv, c_w2 * inv);
        ow[2] = make_float2(0.f, 0.f);
        float2* oi = reinterpret_cast<float2*>(out + NW6 + (size_t)tok * 6);
        oi[0] = make_float2((float)aidx, (float)(8 + bidx));
        oi[1] = make_float2((float)(12 + c1), (float)(12 + c2));
        oi[2] = make_float2(0.f, 0.f);

        atomicAdd(&lcnt[aidx], 1u);
        atomicAdd(&lcnt[8 + bidx], 1u);
        atomicAdd(&lcnt[12 + c1], 1u);
        atomicAdd(&lcnt[12 + c2], 1u);
    }

    __syncthreads();
    if (tid < 16) {
        const unsigned int c = lcnt[tid];
        if (c) atomicAdd(&gcounts[tid], c);
    }
    __syncthreads();

    // Last-block ticket computes the aux loss. Reference bincount includes
    // 2 zero-pad indices/token -> expert 0 gets +2*NTOK; total = 6*NTOK.
    if (tid == 0) {
        __threadfence();
        const unsigned int t = atomicAdd(&gcounts[16], 1u);
        if (t == gridDim.x - 1) {
            const float total = 6.0f * (float)NTOK;
            const float uni = 1.0f / 16.0f;
            float aux = 0.f;
            for (int e = 0; e < 16; ++e) {
                float c = (float)atomicAdd(&gcounts[e], 0u)
                          + (e == 0 ? 2.0f * (float)NTOK : 0.0f);
                aux += uni * (logf(uni) - logf(c / total));
            }
            out[2 * NW6] = aux * 0.01f;
        }
    }
}

extern "C" void kernel_launch(void* const* d_in, const int* in_sizes, int n_in,
                              void* d_out, int out_size, void* d_ws, size_t ws_size,
                              hipStream_t stream)
{
    const float* x  = (const float*)d_in[0];   // (4,4096,2048)
    const float* We = (const float*)d_in[1];   // (16,2048)
    const float* Wg = (const float*)d_in[2];   // (2,2048)
    float* out = (float*)d_out;
    unsigned int* counts = (unsigned int*)d_ws;

    hipMemsetAsync(counts, 0, 17 * sizeof(unsigned int), stream);

    const int blocks = NTOK / 32;              // 8 tok/wave * 4 waves/block
    router_kernel<<<blocks, 256, 0, stream>>>(x, We, Wg, out, counts);
}

// Round 6
// 220.602 us; speedup vs baseline: 1.5214x; 1.5214x over previous
//
#include <hip/hip_runtime.h>
#include <math.h>

#define NTOK  16384
#define NW6   (NTOK * 6)
#define NSEG  4
#define SEGD4 128              // 512 dims / 4 per float4
#define D4    512              // full row in float4
#define SCORES_FLOATS (NSEG * 18 * NTOK)   // 1,179,648 floats = 4.72 MB

#define DOT4(a, b) ((a).x*(b).x + (a).y*(b).y + (a).z*(b).z + (a).w*(b).w)

// DPP row_shl sum-tree: lane i adds lane i+N (out-of-range -> 0). After the
// 4 steps lane 0 of each 16-lane row holds the full row sum. Pure VALU.
template <int CTRL>
__device__ __forceinline__ float dpp_add(float v) {
    int moved = __builtin_amdgcn_update_dpp(0, __float_as_int(v),
                                            CTRL, 0xF, 0xF, true);
    return v + __int_as_float(moved);
}
__device__ __forceinline__ float row_reduce16(float v) {
    v = dpp_add<0x108>(v);   // row_shl:8
    v = dpp_add<0x104>(v);   // row_shl:4
    v = dpp_add<0x102>(v);   // row_shl:2
    v = dpp_add<0x101>(v);   // row_shl:1
    return v;                // full sum valid at lane 0 of each row of 16
}

// ---------------- Phase 1: partial scores per D-segment ----------------
// Block: 256 thr (4 waves), one D-segment (512 dims, 36 KB W in LDS), 64
// tokens. Wave = 4 groups x 16 lanes; each group accumulates 4 tokens.
__global__ __launch_bounds__(256, 3) void scores_kernel(
    const float* __restrict__ x,
    const float* __restrict__ We,
    const float* __restrict__ Wg,
    float* __restrict__ scores)
{
    __shared__ float4 wlds[18 * SEGD4];   // 36,864 B

    const int tid  = threadIdx.x;
    const int seg  = blockIdx.x & 3;
    const int strip = blockIdx.x >> 2;

    const float4* __restrict__ x4  = reinterpret_cast<const float4*>(x);
    const float4* __restrict__ We4 = reinterpret_cast<const float4*>(We);
    const float4* __restrict__ Wg4 = reinterpret_cast<const float4*>(Wg);

    // Stage the 18 x 512-dim W segment into LDS (coalesced, conflict-free).
#pragma unroll
    for (int k = 0; k < 9; ++k) {
        const int idx = k * 256 + tid;        // 0..2303 float4
        const int e = idx >> 7;               // 0..17
        const int d = idx & 127;
        const float4* src = (e < 16) ? (We4 + (size_t)e * D4)
                                     : (Wg4 + (size_t)(e - 16) * D4);
        wlds[idx] = src[seg * SEGD4 + d];
    }
    __syncthreads();

    const int wave = tid >> 6;
    const int lane = tid & 63;
    const int grp  = lane >> 4;
    const int l16  = lane & 15;
    const int tokbase = strip * 64 + wave * 16 + grp * 4;

    const float4* __restrict__ xr0 = x4 + (size_t)(tokbase + 0) * D4 + seg * SEGD4;
    const float4* __restrict__ xr1 = x4 + (size_t)(tokbase + 1) * D4 + seg * SEGD4;
    const float4* __restrict__ xr2 = x4 + (size_t)(tokbase + 2) * D4 + seg * SEGD4;
    const float4* __restrict__ xr3 = x4 + (size_t)(tokbase + 3) * D4 + seg * SEGD4;

    float acc0[18], acc1[18], acc2[18], acc3[18];
#pragma unroll
    for (int e = 0; e < 18; ++e) { acc0[e]=0.f; acc1[e]=0.f; acc2[e]=0.f; acc3[e]=0.f; }

    // 8 iters x 64 dims: 4 coalesced x-loads + 18 broadcast LDS reads + 288 FMA.
#pragma unroll 2
    for (int it = 0; it < 8; ++it) {
        const int off = it * 16 + l16;
        const float4 xv0 = xr0[off];
        const float4 xv1 = xr1[off];
        const float4 xv2 = xr2[off];
        const float4 xv3 = xr3[off];
#pragma unroll
        for (int e = 0; e < 18; ++e) {
            const float4 wv = wlds[e * SEGD4 + off];
            acc0[e] += DOT4(wv, xv0);
            acc1[e] += DOT4(wv, xv1);
            acc2[e] += DOT4(wv, xv2);
            acc3[e] += DOT4(wv, xv3);
        }
    }

    // VALU row-reduce: lane 0 of each 16-lane group gets each full sum.
#pragma unroll
    for (int e = 0; e < 18; ++e) {
        acc0[e] = row_reduce16(acc0[e]);
        acc1[e] = row_reduce16(acc1[e]);
        acc2[e] = row_reduce16(acc2[e]);
        acc3[e] = row_reduce16(acc3[e]);
    }

    if (l16 == 0) {
#pragma unroll
        for (int e = 0; e < 18; ++e) {
            float* p = scores + (size_t)(seg * 18 + e) * NTOK + tokbase;
            p[0] = acc0[e];
            p[1] = acc1[e];
            p[2] = acc2[e];
            p[3] = acc3[e];
        }
    }
}

// ---------------- Phase 2: combine segments + routing + aux ----------------
__global__ __launch_bounds__(256) void route_kernel(
    const float* __restrict__ scores,
    float* __restrict__ out,
    unsigned int* __restrict__ gcounts)
{
    __shared__ unsigned int lcnt[16];
    const int tid = threadIdx.x;
    if (tid < 16) lcnt[tid] = 0u;
    __syncthreads();

    const int tok = blockIdx.x * 256 + tid;

    float s[18];
#pragma unroll
    for (int e = 0; e < 18; ++e) {
        s[e] = scores[(size_t)(0 * 18 + e) * NTOK + tok]
             + scores[(size_t)(1 * 18 + e) * NTOK + tok]
             + scores[(size_t)(2 * 18 + e) * NTOK + tok]
             + scores[(size_t)(3 * 18 + e) * NTOK + tok];
    }

    const float g0 = 1.f / (1.f + expf(-s[16]));
    const float g1 = 1.f / (1.f + expf(-s[17]));

    // --- Group A: experts 0..7, top-1 of softmax ---
    int aidx = 0; float amax = s[0];
#pragma unroll
    for (int i = 1; i < 8; ++i)
        if (s[i] > amax) { amax = s[i]; aidx = i; }
    float asum = 0.f;
#pragma unroll
    for (int i = 0; i < 8; ++i) asum += expf(s[i] - amax);
    const float a_best = 1.f / asum;

    // --- Group B: experts 8..11, top-1, gated by g0 ---
    int bidx = 0; float bmax = s[8];
#pragma unroll
    for (int i = 1; i < 4; ++i)
        if (s[8 + i] > bmax) { bmax = s[8 + i]; bidx = i; }
    float bsum = 0.f;
#pragma unroll
    for (int i = 0; i < 4; ++i) bsum += expf(s[8 + i] - bmax);
    const float b_w = (g0 > 0.15f) ? ((1.f / bsum) * g0) : 0.f;

    // --- Group C: experts 12..15, top-2 of softmax, gated by g1 ---
    int c1 = 0; float cmax = s[12];
#pragma unroll
    for (int i = 1; i < 4; ++i)
        if (s[12 + i] > cmax) { cmax = s[12 + i]; c1 = i; }
    float csum = 0.f;
#pragma unroll
    for (int i = 0; i < 4; ++i) csum += expf(s[12 + i] - cmax);
    int c2 = -1; float c2v = -1e30f;
#pragma unroll
    for (int i = 0; i < 4; ++i)
        if (i != c1 && s[12 + i] > c2v) { c2v = s[12 + i]; c2 = i; }
    const float cg   = (g1 > 0.15f) ? g1 : 0.f;
    const float c_w1 = (1.f / csum) * cg;
    const float c_w2 = (expf(c2v - cmax) / csum) * cg;

    // --- normalize and write ---
    const float inv = 1.f / (a_best + b_w + c_w1 + c_w2 + 1e-8f);
    float2* ow = reinterpret_cast<float2*>(out + (size_t)tok * 6);
    ow[0] = make_float2(a_best * inv, b_w * inv);
    ow[1] = make_float2(c_w1 * inv, c_w2 * inv);
    ow[2] = make_float2(0.f, 0.f);
    float2* oi = reinterpret_cast<float2*>(out + NW6 + (size_t)tok * 6);
    oi[0] = make_float2((float)aidx, (float)(8 + bidx));
    oi[1] = make_float2((float)(12 + c1), (float)(12 + c2));
    oi[2] = make_float2(0.f, 0.f);

    atomicAdd(&lcnt[aidx], 1u);
    atomicAdd(&lcnt[8 + bidx], 1u);
    atomicAdd(&lcnt[12 + c1], 1u);
    atomicAdd(&lcnt[12 + c2], 1u);

    __syncthreads();
    if (tid < 16) {
        const unsigned int c = lcnt[tid];
        if (c) atomicAdd(&gcounts[tid], c);
    }
    __syncthreads();

    // Last-block ticket: aux loss. Reference bincount counts the 2 zero-pad
    // indices per token -> expert 0 gets +2*NTOK; total = 6*NTOK.
    if (tid == 0) {
        __threadfence();
        const unsigned int t = atomicAdd(&gcounts[16], 1u);
        if (t == gridDim.x - 1) {
            const float total = 6.0f * (float)NTOK;
            const float uni = 1.0f / 16.0f;
            float aux = 0.f;
            for (int e = 0; e < 16; ++e) {
                float c = (float)atomicAdd(&gcounts[e], 0u)
                          + (e == 0 ? 2.0f * (float)NTOK : 0.0f);
                aux += uni * (logf(uni) - logf(c / total));
            }
            out[2 * NW6] = aux * 0.01f;
        }
    }
}

extern "C" void kernel_launch(void* const* d_in, const int* in_sizes, int n_in,
                              void* d_out, int out_size, void* d_ws, size_t ws_size,
                              hipStream_t stream)
{
    const float* x  = (const float*)d_in[0];   // (4,4096,2048)
    const float* We = (const float*)d_in[1];   // (16,2048)
    const float* Wg = (const float*)d_in[2];   // (2,2048)
    float* out = (float*)d_out;

    float* scores = (float*)d_ws;                          // 4.72 MB
    unsigned int* counts = (unsigned int*)((char*)d_ws + SCORES_FLOATS * 4);

    hipMemsetAsync(counts, 0, 17 * sizeof(unsigned int), stream);

    // Phase 1: 256 token-strips x 4 D-segments.
    scores_kernel<<<dim3(1024), 256, 0, stream>>>(x, We, Wg, scores);
    // Phase 2 (stream-ordered after phase 1).
    route_kernel<<<dim3(NTOK / 256), 256, 0, stream>>>(scores, out, counts);
}